// Round 15
// baseline (322.192 us; speedup 1.0000x reference)
//
#include <hip/hip_runtime.h>
#include <hip/hip_fp16.h>
#include <cstdint>

// 2-layer GAT, PyG GATConv semantics (concat heads, self-loops, segment softmax).
// R15: DIAGNOSTIC ROUND. gemm pinned at 59-69us across SIX structures (VALU,
// LDS-MFMA, direct-MFMA, no-LDS, reg-staged, fused-att full-line-store),
// independent of K (64 vs 256), all pipes <3% busy. Hand model says <=20us.
// This round launches 4 stripped variants (full-size, outputs overwritten by
// the real pipeline afterwards) to partition the mystery cost:
//   D1 full with __launch_bounds__(256,1)  (regalloc hypothesis)
//   D2 loads-only                          (load-path hypothesis)
//   D3 stores-only                         (store-path hypothesis)
//   D4 shell                               (per-wave fixed-cost hypothesis)
// Real pipeline (= R14) runs after and produces the verified output.

#define CH 4096
#define MAXB 512
#define SCAP 6144

using f16x8 = __attribute__((ext_vector_type(8))) _Float16;
using f32x4 = __attribute__((ext_vector_type(4))) float;

__device__ __forceinline__ float lrelu(float v) { return fmaxf(v, 0.2f * v); }

__global__ void ifill_kernel(int* __restrict__ p, int v, int n) {
  int i = blockIdx.x * blockDim.x + threadIdx.x;
  if (i < n) p[i] = v;
}

// Augmented W'^T [80][K] fp16: c<64: W[k][c]; c=64+hd: W_hd@att_src_hd;
// c=68+hd: W_hd@att_dst_hd; c>=72: 0.
__global__ void wprep2_kernel(const float* __restrict__ W,
                              const float* __restrict__ as,
                              const float* __restrict__ ad,
                              ushort* __restrict__ WT, int K) {
  int i = blockIdx.x * 256 + threadIdx.x;
  if (i >= 80 * K) return;
  int c = i / K, k = i % K;
  float v = 0.f;
  if (c < 64) {
    v = W[k * 64 + c];
  } else if (c < 68) {
    int hd = c - 64;
    for (int j = 0; j < 16; ++j) v += W[k * 64 + hd * 16 + j] * as[hd * 16 + j];
  } else if (c < 72) {
    int hd = c - 68;
    for (int j = 0; j < 16; ++j) v += W[k * 64 + hd * 16 + j] * ad[hd * 16 + j];
  }
  WT[c * K + k] = __half_as_ushort(__float2half_rn(v));
}

__global__ __launch_bounds__(256) void bucket_hist(const int* __restrict__ edst,
                                                   int E, int nbuck,
                                                   int* __restrict__ bucket_cnt) {
  __shared__ int hist[MAXB];
  const int t = threadIdx.x;
  for (int j = t; j < MAXB; j += 256) hist[j] = 0;
  __syncthreads();
  const int base = blockIdx.x * CH;
#pragma unroll
  for (int k = 0; k < CH / 256; ++k) {
    int e = base + k * 256 + t;
    if (e < E) atomicAdd(&hist[edst[e] >> 8], 1);
  }
  __syncthreads();
  for (int j = t; j < nbuck; j += 256) {
    int c = hist[j];
    if (c) atomicAdd(&bucket_cnt[j], c);
  }
}

__global__ __launch_bounds__(512) void bucket_scan(const int* __restrict__ bucket_cnt,
                                                   int* __restrict__ bucket_base,
                                                   int* __restrict__ bucket_cursor,
                                                   int nbuck) {
  __shared__ int part[512];
  const int t = threadIdx.x;
  int v = (t < nbuck) ? bucket_cnt[t] : 0;
  part[t] = v;
  __syncthreads();
  for (int off = 1; off < 512; off <<= 1) {
    int u = (t >= off) ? part[t - off] : 0;
    __syncthreads();
    part[t] += u;
    __syncthreads();
  }
  int ex = part[t] - v;
  if (t <= nbuck) {
    int w = (t < nbuck) ? ex : part[nbuck - 1];
    bucket_base[t] = w;
    if (t < nbuck) bucket_cursor[t] = w;
  }
}

__global__ __launch_bounds__(256) void place_kernel(const int* __restrict__ esrc,
                                                    const int* __restrict__ edst,
                                                    int E, int nbuck,
                                                    int* __restrict__ bucket_cursor,
                                                    unsigned int* __restrict__ pairs) {
  __shared__ int hist[MAXB];
  __shared__ int gbase[MAXB];
  __shared__ int rcnt[MAXB];
  const int t = threadIdx.x;
  for (int j = t; j < MAXB; j += 256) { hist[j] = 0; rcnt[j] = 0; }
  __syncthreads();
  const int base = blockIdx.x * CH;
  int b_[CH / 256];
  unsigned int p_[CH / 256];
#pragma unroll
  for (int k = 0; k < CH / 256; ++k) {
    int e = base + k * 256 + t;
    if (e < E) {
      int d = edst[e];
      int s = esrc[e];
      b_[k] = d >> 8;
      p_[k] = ((unsigned int)s << 8) | (unsigned int)(d & 255);
      atomicAdd(&hist[b_[k]], 1);
    } else {
      b_[k] = -1;
    }
  }
  __syncthreads();
  for (int j = t; j < nbuck; j += 256) {
    int c = hist[j];
    gbase[j] = c ? atomicAdd(&bucket_cursor[j], c) : 0;
  }
  __syncthreads();
#pragma unroll
  for (int k = 0; k < CH / 256; ++k) {
    if (b_[k] >= 0) {
      int r = atomicAdd(&rcnt[b_[k]], 1);
      pairs[gbase[b_[k]] + r] = p_[k];
    }
  }
}

__global__ __launch_bounds__(256) void bucket_build(
    const unsigned int* __restrict__ pairs, const int* __restrict__ bucket_base,
    int* __restrict__ ccol, int* __restrict__ start, int* __restrict__ endp,
    int n) {
  __shared__ int cnt[256];
  __shared__ int ls[256];
  __shared__ int csave[256];
  __shared__ int part[256];
  __shared__ int sorted[SCAP];
  const int t = threadIdx.x;
  const int b = blockIdx.x;
  const int d0 = b << 8;
  const int DR = min(256, n - d0);
  const int in_base = bucket_base[b];
  const int nloc = bucket_base[b + 1] - in_base;
  const int out_base = in_base + d0;

  cnt[t] = (t < DR) ? 1 : 0;
  __syncthreads();
  for (int i = t; i < nloc; i += 256)
    atomicAdd(&cnt[pairs[in_base + i] & 255u], 1);
  __syncthreads();
  int c = cnt[t];
  csave[t] = c;
  part[t] = c;
  __syncthreads();
#pragma unroll
  for (int off = 1; off < 256; off <<= 1) {
    int u = (t >= off) ? part[t - off] : 0;
    __syncthreads();
    part[t] += u;
    __syncthreads();
  }
  ls[t] = part[t] - c;
  __syncthreads();
  if (t < DR) {
    int s = out_base + ls[t];
    start[d0 + t] = s;
    endp[d0 + t] = s + csave[t];
    sorted[ls[t]] = d0 + t;
    cnt[t] = 1;
  }
  __syncthreads();
  for (int i = t; i < nloc; i += 256) {
    unsigned int p = pairs[in_base + i];
    int j = (int)(p & 255u);
    int r = atomicAdd(&cnt[j], 1);
    int pos = ls[j] + r;
    if (pos < SCAP) sorted[pos] = (int)(p >> 8);
  }
  __syncthreads();
  int tot = nloc + DR;
  if (tot > SCAP) tot = SCAP;
  for (int i = t; i < tot; i += 256) ccol[out_base + i] = sorted[i];
}

// ---- GEMM body, variant-stripped ----
// VARIANT 0: full. 1: loads-only. 2: stores-only. 3: shell.
template <int K, bool XHALF, int VARIANT>
__device__ __forceinline__ void gemm_body(
    const void* __restrict__ xin, const ushort* __restrict__ wt,
    __half* __restrict__ h, float* __restrict__ as_, float* __restrict__ ad_,
    int n) {
  constexpr bool DO_LOAD = (VARIANT == 0 || VARIANT == 1);
  constexpr bool DO_MFMA = (VARIANT == 0);
  constexpr bool DO_STORE = (VARIANT == 0 || VARIANT == 2);
  __shared__ _Float16 hs[64 * 88];
  __shared__ float att[64 * 12];
  const int tid = threadIdx.x;
  const int w = tid >> 6;
  const int lane = tid & 63;
  const int lr = lane & 15;
  const int kg = lane >> 4;
  const int row0 = blockIdx.x * 64;

  int rr = row0 + w * 16 + lr;
  if (rr > n - 1) rr = n - 1;

  constexpr int NS = K / 32;
  const ushort* wbase = wt + lr * K + kg * 8;

  f16x8 af[NS] = {};
  if constexpr (DO_LOAD) {
    if constexpr (!XHALF) {
      float4 av[NS][2];
      const float* xp = (const float*)xin + (long long)rr * K + kg * 8;
#pragma unroll
      for (int s = 0; s < NS; ++s) {
        av[s][0] = *(const float4*)(xp + s * 32);
        av[s][1] = *(const float4*)(xp + s * 32 + 4);
      }
#pragma unroll
      for (int s = 0; s < NS; ++s) {
        af[s][0] = (_Float16)av[s][0].x; af[s][1] = (_Float16)av[s][0].y;
        af[s][2] = (_Float16)av[s][0].z; af[s][3] = (_Float16)av[s][0].w;
        af[s][4] = (_Float16)av[s][1].x; af[s][5] = (_Float16)av[s][1].y;
        af[s][6] = (_Float16)av[s][1].z; af[s][7] = (_Float16)av[s][1].w;
      }
    } else {
      const ushort* xp = (const ushort*)xin + (long long)rr * K + kg * 8;
#pragma unroll
      for (int s = 0; s < NS; ++s)
        af[s] = *(const f16x8*)(xp + s * 32);
    }
  }

  f32x4 acc[5] = {};
  if constexpr (VARIANT == 2) {  // fabricated accumulators (no loads)
#pragma unroll
    for (int ct = 0; ct < 5; ++ct)
#pragma unroll
      for (int r = 0; r < 4; ++r)
        acc[ct][r] = (float)((tid * 7 + ct * 4 + r) & 255) * 0.001f;
  }

  if constexpr (DO_MFMA) {
#pragma unroll
    for (int s = 0; s < NS; ++s) {
#pragma unroll
      for (int ct = 0; ct < 5; ++ct) {
        f16x8 b = *(const f16x8*)(wbase + ct * 16 * K + s * 32);
        acc[ct] = __builtin_amdgcn_mfma_f32_16x16x32_f16(af[s], b, acc[ct], 0, 0, 0);
      }
    }
  } else if constexpr (VARIANT == 1) {  // loads-only: B loads + keep-alive
    f16x8 sink = af[0];
#pragma unroll
    for (int s = 0; s < NS; ++s) {
#pragma unroll
      for (int ct = 0; ct < 5; ++ct) {
        f16x8 b = *(const f16x8*)(wbase + ct * 16 * K + s * 32);
        sink += b;
      }
      sink += af[s];
    }
    float fs = 0.f;
#pragma unroll
    for (int j = 0; j < 8; ++j) fs += (float)sink[j];
    asm volatile("" ::"v"(fs));  // keep entire load chain live (rule #17)
  } else if constexpr (VARIANT == 3) {  // shell
    float fs = (float)rr + (float)(unsigned)(uintptr_t)wbase;
    asm volatile("" ::"v"(fs));
  }

  if constexpr (DO_STORE) {
    const int orow = w * 16 + kg * 4;
#pragma unroll
    for (int ct = 0; ct < 4; ++ct)
#pragma unroll
      for (int r = 0; r < 4; ++r)
        hs[(orow + r) * 88 + ct * 16 + lr] = (_Float16)acc[ct][r];
    if (lr < 8) {
#pragma unroll
      for (int r = 0; r < 4; ++r)
        att[(orow + r) * 12 + lr] = acc[4][r];
    }
    __syncthreads();
#pragma unroll
    for (int j = 0; j < 2; ++j) {
      int s = tid + j * 256;
      int row = s >> 3, seg = s & 7;
      if (row0 + row < n)
        *(uint4*)(h + (long long)(row0 + row) * 64 + seg * 8) =
            *(const uint4*)&hs[row * 88 + seg * 8];
    }
    if (tid < 64) {
      if (row0 + tid < n)
        *(float4*)(as_ + (long long)(row0 + tid) * 4) = *(const float4*)&att[tid * 12];
    } else if (tid < 128) {
      int t2 = tid - 64;
      if (row0 + t2 < n)
        *(float4*)(ad_ + (long long)(row0 + t2) * 4) = *(const float4*)&att[t2 * 12 + 4];
    }
  }
}

template <int K, bool XHALF, int VARIANT>
__global__ __launch_bounds__(256) void gemm_mfma(
    const void* __restrict__ xin, const ushort* __restrict__ wt,
    __half* __restrict__ h, float* __restrict__ as_, float* __restrict__ ad_,
    int n) {
  gemm_body<K, XHALF, VARIANT>(xin, wt, h, as_, ad_, n);
}

// D1: identical full body, but min-waves/EU = 1 (VGPR budget up to ~512).
template <int K, bool XHALF>
__global__ __launch_bounds__(256, 1) void gemm_mfma_relaxed(
    const void* __restrict__ xin, const ushort* __restrict__ wt,
    __half* __restrict__ h, float* __restrict__ as_, float* __restrict__ ad_,
    int n) {
  gemm_body<K, XHALF, 0>(xin, wt, h, as_, ad_, n);
}

// Half-wave (32 lanes) per dst node, 2 nodes/wave; lane covers 2 channels via
// __half2. mode 1: relu + fp16 out (layer-2 GEMM input); mode 0: f32 out.
__global__ __launch_bounds__(256) void node_agg_kernel(
    const int* __restrict__ ccol, const int* __restrict__ start,
    const int* __restrict__ endp,
    const float* __restrict__ as_, const float* __restrict__ ad_,
    const __half2* __restrict__ h2, const float* __restrict__ bias,
    float* __restrict__ fout, __half2* __restrict__ hout, int n, int mode) {
  const int node = blockIdx.x * 8 + (threadIdx.x >> 5);
  if (node >= n) return;
  const int hl = threadIdx.x & 31;
  const int hh = hl >> 3;
  const float adv = ad_[node * 4 + hh];
  const int s0i = start[node];
  const int d = endp[node] - s0i;
  const int* cp = ccol + s0i;
  float ax = 0.f, ay = 0.f, den = 0.f;
  int i = 0;
  for (; i + 4 <= d; i += 4) {
    int s0 = cp[i], s1 = cp[i + 1], s2 = cp[i + 2], s3 = cp[i + 3];
    float p0 = __expf(lrelu(as_[s0 * 4 + hh] + adv));
    float p1 = __expf(lrelu(as_[s1 * 4 + hh] + adv));
    float p2 = __expf(lrelu(as_[s2 * 4 + hh] + adv));
    float p3 = __expf(lrelu(as_[s3 * 4 + hh] + adv));
    float2 h0 = __half22float2(h2[s0 * 32 + hl]);
    float2 h1 = __half22float2(h2[s1 * 32 + hl]);
    float2 h2v = __half22float2(h2[s2 * 32 + hl]);
    float2 h3 = __half22float2(h2[s3 * 32 + hl]);
    den += (p0 + p1) + (p2 + p3);
    ax = fmaf(p0, h0.x, ax); ay = fmaf(p0, h0.y, ay);
    ax = fmaf(p1, h1.x, ax); ay = fmaf(p1, h1.y, ay);
    ax = fmaf(p2, h2v.x, ax); ay = fmaf(p2, h2v.y, ay);
    ax = fmaf(p3, h3.x, ax); ay = fmaf(p3, h3.y, ay);
  }
  for (; i < d; ++i) {
    int s0 = cp[i];
    float p0 = __expf(lrelu(as_[s0 * 4 + hh] + adv));
    float2 h0 = __half22float2(h2[s0 * 32 + hl]);
    den += p0;
    ax = fmaf(p0, h0.x, ax); ay = fmaf(p0, h0.y, ay);
  }
  const float inv = 1.0f / (den + 1e-16f);
  float vx = ax * inv + bias[hl * 2];
  float vy = ay * inv + bias[hl * 2 + 1];
  if (mode == 1) {
    vx = fmaxf(vx, 0.f);
    vy = fmaxf(vy, 0.f);
    hout[node * 32 + hl] = __floats2half2_rn(vx, vy);
  } else {
    *(float2*)(fout + node * 64 + hl * 2) = make_float2(vx, vy);
  }
}

extern "C" void kernel_launch(void* const* d_in, const int* in_sizes, int n_in,
                              void* d_out, int out_size, void* d_ws, size_t ws_size,
                              hipStream_t stream) {
  const float* x = (const float*)d_in[0];
  const int* ei = (const int*)d_in[1];
  const float* W1 = (const float*)d_in[2];
  const float* att_s1 = (const float*)d_in[3];
  const float* att_d1 = (const float*)d_in[4];
  const float* b1 = (const float*)d_in[5];
  const float* W2 = (const float*)d_in[6];
  const float* att_s2 = (const float*)d_in[7];
  const float* att_d2 = (const float*)d_in[8];
  const float* b2 = (const float*)d_in[9];

  const int n = in_sizes[0] / 256;  // 100000
  const int E = in_sizes[1] / 2;    // 1600000
  const int* esrc = ei;
  const int* edst = ei + E;
  const int nbuck = (n + 255) >> 8;  // 391

  float* wsf = (float*)d_ws;
  __half* hbuf = (__half*)wsf;
  float* xbuf = wsf + (long long)n * 64;
  float* as_ = xbuf + (long long)n * 64;
  float* ad_ = as_ + (long long)n * 4;
  int* bucket_cnt = (int*)(ad_ + (long long)n * 4);
  int* bucket_base = bucket_cnt + MAXB;
  int* bucket_cursor = bucket_base + MAXB + 1;
  int* start = bucket_cursor + MAXB;
  int* endp = start + n;
  unsigned int* pairs = (unsigned int*)(endp + n);
  int* ccol = (int*)(pairs + E);
  ushort* wt1 = (ushort*)(((uintptr_t)(ccol + E + n) + 15) & ~(uintptr_t)15);
  ushort* wt2 = wt1 + 80 * 256;
  float* out = (float*)d_out;

  const int ebk = (E + CH - 1) / CH;
  const int gb = (n + 63) / 64;
  const int nb = (n + 7) / 8;

  // ---- prep ----
  wprep2_kernel<<<(80 * 256 + 255) / 256, 256, 0, stream>>>(W1, att_s1, att_d1, wt1, 256);
  wprep2_kernel<<<(80 * 64 + 255) / 256, 256, 0, stream>>>(W2, att_s2, att_d2, wt2, 64);

  // ---- CSR bucket build ----
  ifill_kernel<<<(MAXB + 255) / 256, 256, 0, stream>>>(bucket_cnt, 0, MAXB);
  bucket_hist<<<ebk, 256, 0, stream>>>(edst, E, nbuck, bucket_cnt);
  bucket_scan<<<1, 512, 0, stream>>>(bucket_cnt, bucket_base, bucket_cursor, nbuck);
  place_kernel<<<ebk, 256, 0, stream>>>(esrc, edst, E, nbuck, bucket_cursor, pairs);
  bucket_build<<<nbuck, 256, 0, stream>>>(pairs, bucket_base, ccol, start, endp, n);

  // ---- DIAGNOSTICS (outputs overwritten by real gemm1 below) ----
  gemm_mfma_relaxed<256, false><<<gb, 256, 0, stream>>>(x, wt1, hbuf, as_, ad_, n);  // D1
  gemm_mfma<256, false, 1><<<gb, 256, 0, stream>>>(x, wt1, hbuf, as_, ad_, n);       // D2 loads
  gemm_mfma<256, false, 2><<<gb, 256, 0, stream>>>(x, wt1, hbuf, as_, ad_, n);       // D3 stores
  gemm_mfma<256, false, 3><<<gb, 256, 0, stream>>>(x, wt1, hbuf, as_, ad_, n);       // D4 shell

  // ---- layer 1 (real) ----
  gemm_mfma<256, false, 0><<<gb, 256, 0, stream>>>(x, wt1, hbuf, as_, ad_, n);
  node_agg_kernel<<<nb, 256, 0, stream>>>(ccol, start, endp, as_, ad_,
                                          (const __half2*)hbuf, b1,
                                          nullptr, (__half2*)xbuf, n, 1);

  // ---- layer 2 (real) ----
  gemm_mfma<64, true, 0><<<gb, 256, 0, stream>>>(xbuf, wt2, hbuf, as_, ad_, n);
  node_agg_kernel<<<nb, 256, 0, stream>>>(ccol, start, endp, as_, ad_,
                                          (const __half2*)hbuf, b2,
                                          out, nullptr, n, 0);
}

// Round 16
// 204.989 us; speedup vs baseline: 1.5718x; 1.5718x over previous
//
#include <hip/hip_runtime.h>
#include <hip/hip_fp16.h>
#include <cstdint>

// 2-layer GAT, PyG GATConv semantics (concat heads, self-loops, segment softmax).
// R16: persistent MFMA GEMM with REGISTER-RESIDENT B. R15 ablation: loads-only
// fast (~20us), stores-only fast (~7us), shell fast, loads+MFMA = 65us, and
// launch_bounds(256,1) alone doesn't help => cost is serialized B-load->
// waitcnt->MFMA round trips (VGPR=52 can't batch 40 B frags). Fix: 512
// resident blocks grid-stride over row-tiles; all B fragments preloaded into
// registers before the tile loop (loop-invariant => must stay in regs;
// 160 VGPR for K=256 under launch_bounds(256,1)); per tile only batched
// A-loads + register-only MFMAs + LDS-bounced coalesced stores.
// Fused att-dots as extra GEMM columns (R14), fp16 h table (R8),
// channel-paired node_agg (R9), CSR bucketed build (R7).
// Softmax max-subtraction omitted: shift-invariant, |e| <= ~10 so exp() safe in f32.

#define CH 4096
#define MAXB 512
#define SCAP 6144

using f16x8 = __attribute__((ext_vector_type(8))) _Float16;
using f32x4 = __attribute__((ext_vector_type(4))) float;

__device__ __forceinline__ float lrelu(float v) { return fmaxf(v, 0.2f * v); }

__global__ void ifill_kernel(int* __restrict__ p, int v, int n) {
  int i = blockIdx.x * blockDim.x + threadIdx.x;
  if (i < n) p[i] = v;
}

// Augmented W'^T [80][K] fp16: c<64: W[k][c]; c=64+hd: W_hd@att_src_hd;
// c=68+hd: W_hd@att_dst_hd; c>=72: 0.
__global__ void wprep2_kernel(const float* __restrict__ W,
                              const float* __restrict__ as,
                              const float* __restrict__ ad,
                              ushort* __restrict__ WT, int K) {
  int i = blockIdx.x * 256 + threadIdx.x;
  if (i >= 80 * K) return;
  int c = i / K, k = i % K;
  float v = 0.f;
  if (c < 64) {
    v = W[k * 64 + c];
  } else if (c < 68) {
    int hd = c - 64;
    for (int j = 0; j < 16; ++j) v += W[k * 64 + hd * 16 + j] * as[hd * 16 + j];
  } else if (c < 72) {
    int hd = c - 68;
    for (int j = 0; j < 16; ++j) v += W[k * 64 + hd * 16 + j] * ad[hd * 16 + j];
  }
  WT[c * K + k] = __half_as_ushort(__float2half_rn(v));
}

__global__ __launch_bounds__(256) void bucket_hist(const int* __restrict__ edst,
                                                   int E, int nbuck,
                                                   int* __restrict__ bucket_cnt) {
  __shared__ int hist[MAXB];
  const int t = threadIdx.x;
  for (int j = t; j < MAXB; j += 256) hist[j] = 0;
  __syncthreads();
  const int base = blockIdx.x * CH;
#pragma unroll
  for (int k = 0; k < CH / 256; ++k) {
    int e = base + k * 256 + t;
    if (e < E) atomicAdd(&hist[edst[e] >> 8], 1);
  }
  __syncthreads();
  for (int j = t; j < nbuck; j += 256) {
    int c = hist[j];
    if (c) atomicAdd(&bucket_cnt[j], c);
  }
}

__global__ __launch_bounds__(512) void bucket_scan(const int* __restrict__ bucket_cnt,
                                                   int* __restrict__ bucket_base,
                                                   int* __restrict__ bucket_cursor,
                                                   int nbuck) {
  __shared__ int part[512];
  const int t = threadIdx.x;
  int v = (t < nbuck) ? bucket_cnt[t] : 0;
  part[t] = v;
  __syncthreads();
  for (int off = 1; off < 512; off <<= 1) {
    int u = (t >= off) ? part[t - off] : 0;
    __syncthreads();
    part[t] += u;
    __syncthreads();
  }
  int ex = part[t] - v;
  if (t <= nbuck) {
    int w = (t < nbuck) ? ex : part[nbuck - 1];
    bucket_base[t] = w;
    if (t < nbuck) bucket_cursor[t] = w;
  }
}

__global__ __launch_bounds__(256) void place_kernel(const int* __restrict__ esrc,
                                                    const int* __restrict__ edst,
                                                    int E, int nbuck,
                                                    int* __restrict__ bucket_cursor,
                                                    unsigned int* __restrict__ pairs) {
  __shared__ int hist[MAXB];
  __shared__ int gbase[MAXB];
  __shared__ int rcnt[MAXB];
  const int t = threadIdx.x;
  for (int j = t; j < MAXB; j += 256) { hist[j] = 0; rcnt[j] = 0; }
  __syncthreads();
  const int base = blockIdx.x * CH;
  int b_[CH / 256];
  unsigned int p_[CH / 256];
#pragma unroll
  for (int k = 0; k < CH / 256; ++k) {
    int e = base + k * 256 + t;
    if (e < E) {
      int d = edst[e];
      int s = esrc[e];
      b_[k] = d >> 8;
      p_[k] = ((unsigned int)s << 8) | (unsigned int)(d & 255);
      atomicAdd(&hist[b_[k]], 1);
    } else {
      b_[k] = -1;
    }
  }
  __syncthreads();
  for (int j = t; j < nbuck; j += 256) {
    int c = hist[j];
    gbase[j] = c ? atomicAdd(&bucket_cursor[j], c) : 0;
  }
  __syncthreads();
#pragma unroll
  for (int k = 0; k < CH / 256; ++k) {
    if (b_[k] >= 0) {
      int r = atomicAdd(&rcnt[b_[k]], 1);
      pairs[gbase[b_[k]] + r] = p_[k];
    }
  }
}

__global__ __launch_bounds__(256) void bucket_build(
    const unsigned int* __restrict__ pairs, const int* __restrict__ bucket_base,
    int* __restrict__ ccol, int* __restrict__ start, int* __restrict__ endp,
    int n) {
  __shared__ int cnt[256];
  __shared__ int ls[256];
  __shared__ int csave[256];
  __shared__ int part[256];
  __shared__ int sorted[SCAP];
  const int t = threadIdx.x;
  const int b = blockIdx.x;
  const int d0 = b << 8;
  const int DR = min(256, n - d0);
  const int in_base = bucket_base[b];
  const int nloc = bucket_base[b + 1] - in_base;
  const int out_base = in_base + d0;

  cnt[t] = (t < DR) ? 1 : 0;
  __syncthreads();
  for (int i = t; i < nloc; i += 256)
    atomicAdd(&cnt[pairs[in_base + i] & 255u], 1);
  __syncthreads();
  int c = cnt[t];
  csave[t] = c;
  part[t] = c;
  __syncthreads();
#pragma unroll
  for (int off = 1; off < 256; off <<= 1) {
    int u = (t >= off) ? part[t - off] : 0;
    __syncthreads();
    part[t] += u;
    __syncthreads();
  }
  ls[t] = part[t] - c;
  __syncthreads();
  if (t < DR) {
    int s = out_base + ls[t];
    start[d0 + t] = s;
    endp[d0 + t] = s + csave[t];
    sorted[ls[t]] = d0 + t;
    cnt[t] = 1;
  }
  __syncthreads();
  for (int i = t; i < nloc; i += 256) {
    unsigned int p = pairs[in_base + i];
    int j = (int)(p & 255u);
    int r = atomicAdd(&cnt[j], 1);
    int pos = ls[j] + r;
    if (pos < SCAP) sorted[pos] = (int)(p >> 8);
  }
  __syncthreads();
  int tot = nloc + DR;
  if (tot > SCAP) tot = SCAP;
  for (int i = t; i < tot; i += 256) ccol[out_base + i] = sorted[i];
}

// Persistent MFMA GEMM, register-resident B. Grid-stride over 64-row tiles.
// Per tile: batched A loads -> register-only MFMA chain (5 col-tiles: 64 W
// cols + 8 att cols) -> LDS bounce -> full-line coalesced stores.
// Fragments: A row=lane&15, k=(lane>>4)*8+j; B col=lane&15 same k;
// D col=lane&15, row=(lane>>4)*4+reg.
template <int K, bool XHALF>
__global__ __launch_bounds__(256, 1) void gemm_mfma(
    const void* __restrict__ xin, const ushort* __restrict__ wt,
    __half* __restrict__ h, float* __restrict__ as_, float* __restrict__ ad_,
    int n, int ntiles) {
  __shared__ _Float16 hs[64 * 88];
  __shared__ float att[64 * 12];
  const int tid = threadIdx.x;
  const int w = tid >> 6;
  const int lane = tid & 63;
  const int lr = lane & 15;
  const int kg = lane >> 4;

  constexpr int NS = K / 32;
  const ushort* wbase = wt + lr * K + kg * 8;

  // ---- Preload ALL B fragments: loop-invariant => register-resident ----
  f16x8 bf[5][NS];
#pragma unroll
  for (int ct = 0; ct < 5; ++ct)
#pragma unroll
    for (int s = 0; s < NS; ++s)
      bf[ct][s] = *(const f16x8*)(wbase + ct * 16 * K + s * 32);

  for (int tile = blockIdx.x; tile < ntiles; tile += gridDim.x) {
    const int row0 = tile * 64;
    int rr = row0 + w * 16 + lr;
    if (rr > n - 1) rr = n - 1;  // tail rows duplicate row n-1; stores guarded

    // ---- Batched A loads (independent addresses, single drain) ----
    f16x8 af[NS];
    if constexpr (!XHALF) {
      float4 av[NS][2];
      const float* xp = (const float*)xin + (long long)rr * K + kg * 8;
#pragma unroll
      for (int s = 0; s < NS; ++s) {
        av[s][0] = *(const float4*)(xp + s * 32);
        av[s][1] = *(const float4*)(xp + s * 32 + 4);
      }
#pragma unroll
      for (int s = 0; s < NS; ++s) {
        af[s][0] = (_Float16)av[s][0].x; af[s][1] = (_Float16)av[s][0].y;
        af[s][2] = (_Float16)av[s][0].z; af[s][3] = (_Float16)av[s][0].w;
        af[s][4] = (_Float16)av[s][1].x; af[s][5] = (_Float16)av[s][1].y;
        af[s][6] = (_Float16)av[s][1].z; af[s][7] = (_Float16)av[s][1].w;
      }
    } else {
      const ushort* xp = (const ushort*)xin + (long long)rr * K + kg * 8;
#pragma unroll
      for (int s = 0; s < NS; ++s)
        af[s] = *(const f16x8*)(xp + s * 32);
    }

    // ---- Register-only MFMA chain ----
    f32x4 acc[5] = {};
#pragma unroll
    for (int s = 0; s < NS; ++s)
#pragma unroll
      for (int ct = 0; ct < 5; ++ct)
        acc[ct] = __builtin_amdgcn_mfma_f32_16x16x32_f16(af[s], bf[ct][s], acc[ct], 0, 0, 0);

    // ---- Epilogue: LDS bounce -> full-line coalesced stores ----
    const int orow = w * 16 + kg * 4;
#pragma unroll
    for (int ct = 0; ct < 4; ++ct)
#pragma unroll
      for (int r = 0; r < 4; ++r)
        hs[(orow + r) * 88 + ct * 16 + lr] = (_Float16)acc[ct][r];
    if (lr < 8) {
#pragma unroll
      for (int r = 0; r < 4; ++r)
        att[(orow + r) * 12 + lr] = acc[4][r];
    }
    __syncthreads();
#pragma unroll
    for (int j = 0; j < 2; ++j) {
      int s = tid + j * 256;
      int row = s >> 3, seg = s & 7;
      if (row0 + row < n)
        *(uint4*)(h + (long long)(row0 + row) * 64 + seg * 8) =
            *(const uint4*)&hs[row * 88 + seg * 8];
    }
    if (tid < 64) {
      if (row0 + tid < n)
        *(float4*)(as_ + (long long)(row0 + tid) * 4) = *(const float4*)&att[tid * 12];
    } else if (tid < 128) {
      int t2 = tid - 64;
      if (row0 + t2 < n)
        *(float4*)(ad_ + (long long)(row0 + t2) * 4) = *(const float4*)&att[t2 * 12 + 4];
    }
    __syncthreads();  // LDS reads done before next tile overwrites
  }
}

// Half-wave (32 lanes) per dst node, 2 nodes/wave; lane covers 2 channels via
// __half2. mode 1: relu + fp16 out (layer-2 GEMM input); mode 0: f32 out.
__global__ __launch_bounds__(256) void node_agg_kernel(
    const int* __restrict__ ccol, const int* __restrict__ start,
    const int* __restrict__ endp,
    const float* __restrict__ as_, const float* __restrict__ ad_,
    const __half2* __restrict__ h2, const float* __restrict__ bias,
    float* __restrict__ fout, __half2* __restrict__ hout, int n, int mode) {
  const int node = blockIdx.x * 8 + (threadIdx.x >> 5);
  if (node >= n) return;
  const int hl = threadIdx.x & 31;
  const int hh = hl >> 3;
  const float adv = ad_[node * 4 + hh];
  const int s0i = start[node];
  const int d = endp[node] - s0i;
  const int* cp = ccol + s0i;
  float ax = 0.f, ay = 0.f, den = 0.f;
  int i = 0;
  for (; i + 4 <= d; i += 4) {
    int s0 = cp[i], s1 = cp[i + 1], s2 = cp[i + 2], s3 = cp[i + 3];
    float p0 = __expf(lrelu(as_[s0 * 4 + hh] + adv));
    float p1 = __expf(lrelu(as_[s1 * 4 + hh] + adv));
    float p2 = __expf(lrelu(as_[s2 * 4 + hh] + adv));
    float p3 = __expf(lrelu(as_[s3 * 4 + hh] + adv));
    float2 h0 = __half22float2(h2[s0 * 32 + hl]);
    float2 h1 = __half22float2(h2[s1 * 32 + hl]);
    float2 h2v = __half22float2(h2[s2 * 32 + hl]);
    float2 h3 = __half22float2(h2[s3 * 32 + hl]);
    den += (p0 + p1) + (p2 + p3);
    ax = fmaf(p0, h0.x, ax); ay = fmaf(p0, h0.y, ay);
    ax = fmaf(p1, h1.x, ax); ay = fmaf(p1, h1.y, ay);
    ax = fmaf(p2, h2v.x, ax); ay = fmaf(p2, h2v.y, ay);
    ax = fmaf(p3, h3.x, ax); ay = fmaf(p3, h3.y, ay);
  }
  for (; i < d; ++i) {
    int s0 = cp[i];
    float p0 = __expf(lrelu(as_[s0 * 4 + hh] + adv));
    float2 h0 = __half22float2(h2[s0 * 32 + hl]);
    den += p0;
    ax = fmaf(p0, h0.x, ax); ay = fmaf(p0, h0.y, ay);
  }
  const float inv = 1.0f / (den + 1e-16f);
  float vx = ax * inv + bias[hl * 2];
  float vy = ay * inv + bias[hl * 2 + 1];
  if (mode == 1) {
    vx = fmaxf(vx, 0.f);
    vy = fmaxf(vy, 0.f);
    hout[node * 32 + hl] = __floats2half2_rn(vx, vy);
  } else {
    *(float2*)(fout + node * 64 + hl * 2) = make_float2(vx, vy);
  }
}

extern "C" void kernel_launch(void* const* d_in, const int* in_sizes, int n_in,
                              void* d_out, int out_size, void* d_ws, size_t ws_size,
                              hipStream_t stream) {
  const float* x = (const float*)d_in[0];
  const int* ei = (const int*)d_in[1];
  const float* W1 = (const float*)d_in[2];
  const float* att_s1 = (const float*)d_in[3];
  const float* att_d1 = (const float*)d_in[4];
  const float* b1 = (const float*)d_in[5];
  const float* W2 = (const float*)d_in[6];
  const float* att_s2 = (const float*)d_in[7];
  const float* att_d2 = (const float*)d_in[8];
  const float* b2 = (const float*)d_in[9];

  const int n = in_sizes[0] / 256;  // 100000
  const int E = in_sizes[1] / 2;    // 1600000
  const int* esrc = ei;
  const int* edst = ei + E;
  const int nbuck = (n + 255) >> 8;  // 391

  float* wsf = (float*)d_ws;
  __half* hbuf = (__half*)wsf;
  float* xbuf = wsf + (long long)n * 64;
  float* as_ = xbuf + (long long)n * 64;
  float* ad_ = as_ + (long long)n * 4;
  int* bucket_cnt = (int*)(ad_ + (long long)n * 4);
  int* bucket_base = bucket_cnt + MAXB;
  int* bucket_cursor = bucket_base + MAXB + 1;
  int* start = bucket_cursor + MAXB;
  int* endp = start + n;
  unsigned int* pairs = (unsigned int*)(endp + n);
  int* ccol = (int*)(pairs + E);
  ushort* wt1 = (ushort*)(((uintptr_t)(ccol + E + n) + 15) & ~(uintptr_t)15);
  ushort* wt2 = wt1 + 80 * 256;
  float* out = (float*)d_out;

  const int ebk = (E + CH - 1) / CH;
  const int ntiles = (n + 63) / 64;  // 1563
  const int gemm_blocks = 512;       // 2 resident blocks/CU, grid-stride tiles
  const int nb = (n + 7) / 8;

  // ---- prep ----
  wprep2_kernel<<<(80 * 256 + 255) / 256, 256, 0, stream>>>(W1, att_s1, att_d1, wt1, 256);
  wprep2_kernel<<<(80 * 64 + 255) / 256, 256, 0, stream>>>(W2, att_s2, att_d2, wt2, 64);

  // ---- CSR bucket build ----
  ifill_kernel<<<(MAXB + 255) / 256, 256, 0, stream>>>(bucket_cnt, 0, MAXB);
  bucket_hist<<<ebk, 256, 0, stream>>>(edst, E, nbuck, bucket_cnt);
  bucket_scan<<<1, 512, 0, stream>>>(bucket_cnt, bucket_base, bucket_cursor, nbuck);
  place_kernel<<<ebk, 256, 0, stream>>>(esrc, edst, E, nbuck, bucket_cursor, pairs);
  bucket_build<<<nbuck, 256, 0, stream>>>(pairs, bucket_base, ccol, start, endp, n);

  // ---- layer 1 ----
  gemm_mfma<256, false><<<gemm_blocks, 256, 0, stream>>>(x, wt1, hbuf, as_, ad_, n, ntiles);
  node_agg_kernel<<<nb, 256, 0, stream>>>(ccol, start, endp, as_, ad_,
                                          (const __half2*)hbuf, b1,
                                          nullptr, (__half2*)xbuf, n, 1);

  // ---- layer 2 ----
  gemm_mfma<64, true><<<gemm_blocks, 256, 0, stream>>>(xbuf, wt2, hbuf, as_, ad_, n, ntiles);
  node_agg_kernel<<<nb, 256, 0, stream>>>(ccol, start, endp, as_, ad_,
                                          (const __half2*)hbuf, b2,
                                          out, nullptr, n, 0);
}